// Round 2
// baseline (523.126 us; speedup 1.0000x reference)
//
#include <hip/hip_runtime.h>

#define B_ 64
#define T_ 2000
#define V_ 512
#define L_ 200
#define CPR 7  // producer waves == chunks per round; 8 timesteps per chunk

// Fused CTC, barrier-paced producer/consumer (NO spin-waits, NO LDS atomics).
// Block b handles batch b. Waves 0..6 produce softmax+gather chunks into a
// double-buffered LDS ring; wave 7 runs the block-floating-point alpha
// recursion on the chunks produced in the previous round. One __syncthreads
// per round, hit by all waves from converged top-level code. Logits are
// read-only (no harness restore); no fp16 HBM round trip.

typedef _Float16 half4 __attribute__((ext_vector_type(4)));

__device__ __forceinline__ float dpp_shr1_f(float x) {  // lane i <- lane i-1; lane0 <- 0
  return __int_as_float(__builtin_amdgcn_update_dpp(0, __float_as_int(x), 0x138, 0xf, 0xf, true));
}
__device__ __forceinline__ int dpp_shr1_i(int x) {
  return __builtin_amdgcn_update_dpp(0, x, 0x138, 0xf, 0xf, true);
}
#define DPPADD(v, ctrl, rmask)                                                              \
  v += __int_as_float(__builtin_amdgcn_update_dpp(0, __float_as_int(v), ctrl, rmask, 0xf, true));

__global__ void kz(float* __restrict__ out) { out[0] = 0.0f; }

__global__ __launch_bounds__(512, 1) void ctc_fused(const float* __restrict__ logits,
                                                    const int* __restrict__ lens,
                                                    const int* __restrict__ targets,
                                                    float* __restrict__ out) {
  const int b = blockIdx.x;
  const int wid = threadIdx.x >> 6;
  const int lane = threadIdx.x & 63;

  __shared__ __align__(16) _Float16 ring[2][CPR][8][256];  // 56 KB gathered fp16 probs
  __shared__ __align__(16) float ringbl[2][CPR][8];        // blank probs per timestep
  __shared__ int cmp[256];                                 // compacted nonzero targets
  __shared__ int tl_s;                                     // target length
  __shared__ float sval[512];                              // readout scratch
  __shared__ int sE[64];

  // ---- wave 0: compact targets (single-wave; LDS ops from one wave are ordered) ----
  if (wid == 0) {
    cmp[lane] = 0; cmp[64 + lane] = 0; cmp[128 + lane] = 0; cmp[192 + lane] = 0;
    int base = 0;
#pragma unroll
    for (int cc = 0; cc < 4; ++cc) {
      const int l = cc * 64 + lane;
      const int v = (l < L_) ? targets[b * L_ + l] : 0;
      const unsigned long long mk = __ballot(v != 0);
      const int pos = base + __popcll(mk & ((1ull << lane) - 1ull));
      if (v != 0) cmp[pos] = v;
      base += __popcll(mk);
    }
    if (lane == 0) tl_s = base;
  }
  __syncthreads();

  const int len = lens[b];
  const int nfull = len >> 3;
  const int rem = len & 7;
  const int nch = nfull + (rem ? 1 : 0);
  const int R = (nch + CPR - 1) / CPR;  // production rounds
  const int4 c4 = *(const int4*)(&cmp[4 * lane]);

  const int l0 = 4 * lane;
  const bool v0 = l0 + 0 < L_, v1 = l0 + 1 < L_, v2 = l0 + 2 < L_, v3 = l0 + 3 < L_;

  // ---- consumer state (live on wave CPR only) ----
  float a0 = 0.f, a1 = 0.f, a2 = 0.f, a3 = 0.f, a4 = 0.f, a5 = 0.f, a6 = 0.f, a7 = 0.f;
  int E = 0;         // a_true = a_reg * 2^E (per lane)
  float fac = 1.0f;  // 2^(E_prev_lane - E_this_lane)
  float m0 = 0.f, m1 = 0.f, m2 = 0.f, m3 = 0.f;
  half4 LB0[8], LB1[8];
  float4 BLa0, BLb0, BLa1, BLb1;

  if (wid == CPR) {
    const int cm1 = __shfl_up(c4.w, 1);
    m0 = (lane > 0 && c4.x != 0 && c4.x != cm1) ? 1.0f : 0.0f;
    m1 = (c4.y != 0 && c4.y != c4.x) ? 1.0f : 0.0f;
    m2 = (c4.z != 0 && c4.z != c4.y) ? 1.0f : 0.0f;
    m3 = (c4.w != 0 && c4.w != c4.z) ? 1.0f : 0.0f;
    // Seed: with a0=1 on lane 0, chunk-0 step u=0 computes exactly the init
    // (n0 = 1*pb0, n1 = 1*q1, rest 0) -> no special prologue in the hot loop.
    if (lane == 0) a0 = 1.0f;
  }

  // ---- producer body: build chunk rp*CPR+wid of round rp into ring[rp&1][wid] ----
  auto produce = [&](int rp) {
    const int c = rp * CPR + wid;
    if (c >= nch) return;
    const int buf = rp & 1;
    const float* rowp = logits + (size_t)b * (T_ * V_) + (size_t)c * (8 * V_);
    float4 X[16];
    float G[32];
#pragma unroll
    for (int r = 0; r < 8; ++r) {  // issue all row loads up front (one HBM latency)
      X[2 * r] = *(const float4*)(rowp + r * V_ + 4 * lane);
      X[2 * r + 1] = *(const float4*)(rowp + r * V_ + 256 + 4 * lane);
    }
#pragma unroll
    for (int r = 0; r < 8; ++r) {  // label gathers: same lines as X, L1/MSHR-merged
      G[4 * r + 0] = rowp[r * V_ + c4.x];
      G[4 * r + 1] = rowp[r * V_ + c4.y];
      G[4 * r + 2] = rowp[r * V_ + c4.z];
      G[4 * r + 3] = rowp[r * V_ + c4.w];
    }
#pragma unroll
    for (int r = 0; r < 8; ++r) {
      const float4 xe = X[2 * r], xo = X[2 * r + 1];
      const float e0 = __expf(xe.x);
      float s = ((e0 + __expf(xe.y)) + (__expf(xe.z) + __expf(xe.w))) +
                ((__expf(xo.x) + __expf(xo.y)) + (__expf(xo.z) + __expf(xo.w)));
      DPPADD(s, 0x111, 0xf); DPPADD(s, 0x112, 0xf); DPPADD(s, 0x114, 0xf);
      DPPADD(s, 0x118, 0xf); DPPADD(s, 0x142, 0xa); DPPADD(s, 0x143, 0xc);
      const float sum = __int_as_float(__builtin_amdgcn_readlane(__float_as_int(s), 63));
      const float inv = 32.0f / sum;  // same x32 prescale as verified kernel
      half4 h;
      h.x = (_Float16)(v0 ? __expf(G[4 * r + 0]) * inv : 0.0f);
      h.y = (_Float16)(v1 ? __expf(G[4 * r + 1]) * inv : 0.0f);
      h.z = (_Float16)(v2 ? __expf(G[4 * r + 2]) * inv : 0.0f);
      h.w = (_Float16)(v3 ? __expf(G[4 * r + 3]) * inv : 0.0f);
      *(half4*)(&ring[buf][wid][r][4 * lane]) = h;
      if (lane == 0) ringbl[buf][wid][r] = e0 * inv;  // blank prob (class 0)
    }
  };

#define LDCHUNK(S, BUF, K)                                                   \
  {                                                                          \
    const int bf_ = (BUF), kk_ = (K);                                        \
    _Pragma("unroll") for (int u = 0; u < 8; ++u)                            \
        LB##S[u] = *(const half4*)(&ring[bf_][kk_][u][4 * lane]);            \
    BLa##S = *(const float4*)(&ringbl[bf_][kk_][0]);                         \
    BLb##S = *(const float4*)(&ringbl[bf_][kk_][4]);                         \
  }

#define STEP8(S, CIDX, MASKED)                                               \
  {                                                                          \
    const int tf_ = (CIDX) * 8;                                              \
    const float blv_[8] = {BLa##S.x, BLa##S.y, BLa##S.z, BLa##S.w,           \
                           BLb##S.x, BLb##S.y, BLb##S.z, BLb##S.w};          \
    _Pragma("unroll") for (int u = 0; u < 8; ++u) {                          \
      const half4 hq = LB##S[u];                                             \
      const float qx = (float)hq.x, qy = (float)hq.y;                        \
      const float qz = (float)hq.z, qw = (float)hq.w;                        \
      const float pbv = blv_[u];                                             \
      const float s1 = dpp_shr1_f(a7) * fac;  /* lane0 -> 0 */               \
      float n0 = (a0 + s1) * pbv;                                            \
      float n1 = fmaf(m0, s1, a0 + a1) * qx;                                 \
      float n2 = (a2 + a1) * pbv;                                            \
      float n3 = fmaf(m1, a1, a2 + a3) * qy;                                 \
      float n4 = (a4 + a3) * pbv;                                            \
      float n5 = fmaf(m2, a3, a4 + a5) * qz;                                 \
      float n6 = (a6 + a5) * pbv;                                            \
      float n7 = fmaf(m3, a5, a6 + a7) * qw;                                 \
      if (MASKED) {                                                          \
        const bool act = (tf_ + u) < len;                                    \
        n0 = act ? n0 : a0; n1 = act ? n1 : a1;                              \
        n2 = act ? n2 : a2; n3 = act ? n3 : a3;                              \
        n4 = act ? n4 : a4; n5 = act ? n5 : a5;                              \
        n6 = act ? n6 : a6; n7 = act ? n7 : a7;                              \
      }                                                                      \
      a0 = n0; a1 = n1; a2 = n2; a3 = n3;                                    \
      a4 = n4; a5 = n5; a6 = n6; a7 = n7;                                    \
    }                                                                        \
  }

#define RENORM                                                               \
  {                                                                          \
    const float mx = fmaxf(fmaxf(fmaxf(a0, a1), fmaxf(a2, a3)),              \
                           fmaxf(fmaxf(a4, a5), fmaxf(a6, a7)));             \
    const bool dead = (mx == 0.0f);                                          \
    int e_ = (int)((__float_as_uint(mx) >> 23) & 0xff) - 127;                \
    if (dead) e_ = 0;                                                        \
    const float sc_ = __int_as_float((unsigned)(127 - e_) << 23);            \
    a0 *= sc_; a1 *= sc_; a2 *= sc_; a3 *= sc_;                              \
    a4 *= sc_; a5 *= sc_; a6 *= sc_; a7 *= sc_;                              \
    const int En_ = E + e_;                                                  \
    const int EnP_ = dpp_shr1_i(En_);                                        \
    E = dead ? EnP_ : En_;                                                   \
    const int Ep_ = dpp_shr1_i(E);                                           \
    const int d_ = Ep_ - E;                                                  \
    int dc_ = d_ < -126 ? -126 : (d_ > 126 ? 126 : d_);                      \
    fac = (d_ < -126) ? 0.0f : __int_as_float((unsigned)(dc_ + 127) << 23);  \
  }

  // ================= barrier-paced pipeline =================
  if (wid < CPR) produce(0);
  __syncthreads();

  for (int r = 0; r < R; ++r) {
    if (wid < CPR) {
      if (r + 1 < R) produce(r + 1);
    } else {
      // consume the full (unmasked) chunks of round r from ring[r&1]
      const int c0 = r * CPR;
      int kn = nfull - c0;
      if (kn > CPR) kn = CPR;
      if (kn > 0) {
        LDCHUNK(0, r & 1, 0);
        for (int k = 0; k < kn; ++k) {  // ping-pong prefetch within the round
          if (k & 1) {
            if (k + 1 < kn) LDCHUNK(0, r & 1, k + 1);
            STEP8(1, 0, 0);
          } else {
            if (k + 1 < kn) LDCHUNK(1, r & 1, k + 1);
            STEP8(0, 0, 0);
          }
          RENORM;
        }
      }
    }
    __syncthreads();
  }

  if (wid == CPR) {
    if (rem) {  // deferred masked tail chunk; its ring slot was never overwritten
      const int cM = nfull;
      const int rM = cM / CPR;
      const int kM = cM - rM * CPR;
      LDCHUNK(0, rM & 1, kM);
      STEP8(0, cM, 1);
    }
    // ---- readout (single wave; in-wave LDS ordering) ----
    sval[lane * 8 + 0] = a0; sval[lane * 8 + 1] = a1;
    sval[lane * 8 + 2] = a2; sval[lane * 8 + 3] = a3;
    sval[lane * 8 + 4] = a4; sval[lane * 8 + 5] = a5;
    sval[lane * 8 + 6] = a6; sval[lane * 8 + 7] = a7;
    sE[lane] = E;
    asm volatile("s_waitcnt lgkmcnt(0)" ::: "memory");
    if (lane == 0) {
      const int tl = tl_s;
      const int e1 = 2 * tl;
      const int e2 = e1 - 1;
      const float v1r = sval[e1];
      const int E1 = sE[e1 >> 3];
      const float v2r = (e2 >= 0) ? sval[e2] : 0.0f;
      const int E2 = (e2 >= 0) ? sE[e2 >> 3] : E1;
      const int Em = (E1 > E2) ? E1 : E2;
      const float v = ldexpf(v1r, E1 - Em) + ldexpf(v2r, E2 - Em);
      // subtract len*ln(32) for the uniform x32 prob prescale
      const float ll = __logf(v) + (float)Em * 0.69314718056f - (float)len * 3.46573590280f;
      atomicAdd(out, -ll);
    }
  }
#undef LDCHUNK
#undef STEP8
#undef RENORM
}

extern "C" void kernel_launch(void* const* d_in, const int* in_sizes, int n_in,
                              void* d_out, int out_size, void* d_ws, size_t ws_size,
                              hipStream_t stream) {
  const float* logits = (const float*)d_in[0];     // [B,T,V] fp32 — read-only
  const int* input_lengths = (const int*)d_in[1];  // [B]
  const int* targets = (const int*)d_in[2];        // [B,L]
  float* out = (float*)d_out;                      // [1]
  (void)d_ws; (void)ws_size; (void)in_sizes; (void)n_in; (void)out_size;

  kz<<<1, 1, 0, stream>>>(out);
  ctc_fused<<<B_, 512, 0, stream>>>(logits, input_lengths, targets, out);
}

// Round 3
// 466.974 us; speedup vs baseline: 1.1202x; 1.1202x over previous
//
#include <hip/hip_runtime.h>

#define B_ 64
#define T_ 2000
#define V_ 512
#define L_ 200
#define CPR 7  // producer waves == chunks per round; 8 timesteps per chunk

// Fused CTC, barrier-paced producer/consumer (no spin-waits, no LDS atomics).
// Block b handles batch b. Waves 0..6 produce softmax+gather chunks into a
// double-buffered fp32 LDS ring; wave 7 runs the block-floating-point alpha
// recursion on the chunks produced the previous round. Label gather is done
// from a per-wave LDS scratch of the row exponentials (NOT from global/L1 —
// that serialized ~64 lines/instr through the single per-CU L1 and was the
// round-2 bottleneck). Logits stay read-only; no fp16 HBM round trip.

__device__ __forceinline__ float dpp_shr1_f(float x) {  // lane i <- lane i-1; lane0 <- 0
  return __int_as_float(__builtin_amdgcn_update_dpp(0, __float_as_int(x), 0x138, 0xf, 0xf, true));
}
__device__ __forceinline__ int dpp_shr1_i(int x) {
  return __builtin_amdgcn_update_dpp(0, x, 0x138, 0xf, 0xf, true);
}
#define DPPADD(v, ctrl, rmask)                                                              \
  v += __int_as_float(__builtin_amdgcn_update_dpp(0, __float_as_int(v), ctrl, rmask, 0xf, true));

__global__ void kz(float* __restrict__ out) { out[0] = 0.0f; }

__global__ __launch_bounds__(512, 1) void ctc_fused(const float* __restrict__ logits,
                                                    const int* __restrict__ lens,
                                                    const int* __restrict__ targets,
                                                    float* __restrict__ out) {
  const int b = blockIdx.x;
  const int wid = threadIdx.x >> 6;
  const int lane = threadIdx.x & 63;

  __shared__ __align__(16) float ring[2][CPR][8][256];  // 112 KB gathered fp32 probs
  __shared__ __align__(16) float ringbl[2][CPR][8];     // blank probs per timestep
  __shared__ __align__(16) float scr[CPR][2][512];      // 28 KB per-producer exp scratch
  __shared__ int cmp[256];                              // compacted nonzero targets
  __shared__ int tl_s;                                  // target length
  __shared__ float sval[512];                           // readout scratch
  __shared__ int sE[64];

  // ---- wave 0: compact targets ----
  if (wid == 0) {
    cmp[lane] = 0; cmp[64 + lane] = 0; cmp[128 + lane] = 0; cmp[192 + lane] = 0;
    int base = 0;
#pragma unroll
    for (int cc = 0; cc < 4; ++cc) {
      const int l = cc * 64 + lane;
      const int v = (l < L_) ? targets[b * L_ + l] : 0;
      const unsigned long long mk = __ballot(v != 0);
      const int pos = base + __popcll(mk & ((1ull << lane) - 1ull));
      if (v != 0) cmp[pos] = v;
      base += __popcll(mk);
    }
    if (lane == 0) tl_s = base;
  }
  __syncthreads();

  const int len = lens[b];
  const int nfull = len >> 3;
  const int rem = len & 7;
  const int nch = nfull + (rem ? 1 : 0);
  const int R = (nch + CPR - 1) / CPR;  // production rounds
  const int4 c4 = *(const int4*)(&cmp[4 * lane]);

  const int l0 = 4 * lane;
  const bool v0 = l0 + 0 < L_, v1 = l0 + 1 < L_, v2 = l0 + 2 < L_, v3 = l0 + 3 < L_;

  // ---- consumer state (live on wave CPR only) ----
  float a0 = 0.f, a1 = 0.f, a2 = 0.f, a3 = 0.f, a4 = 0.f, a5 = 0.f, a6 = 0.f, a7 = 0.f;
  int E = 0;         // a_true = a_reg * 2^E (per lane)
  float fac = 1.0f;  // 2^(E_prev_lane - E_this_lane)
  float m0 = 0.f, m1 = 0.f, m2 = 0.f, m3 = 0.f;
  float4 LQ0[8], LQ1[8];
  float4 BLa0, BLb0, BLa1, BLb1;

  if (wid == CPR) {
    const int cm1 = __shfl_up(c4.w, 1);
    m0 = (lane > 0 && c4.x != 0 && c4.x != cm1) ? 1.0f : 0.0f;
    m1 = (c4.y != 0 && c4.y != c4.x) ? 1.0f : 0.0f;
    m2 = (c4.z != 0 && c4.z != c4.y) ? 1.0f : 0.0f;
    m3 = (c4.w != 0 && c4.w != c4.z) ? 1.0f : 0.0f;
    // Seed: a0=1 on lane 0 makes chunk-0 step u=0 reproduce the init exactly.
    if (lane == 0) a0 = 1.0f;
    __builtin_amdgcn_s_setprio(1);  // consumer is the critical wave on its SIMD
  }

  // ---- producer body: build chunk rp*CPR+wid into ring[rp&1][wid] ----
  auto produce = [&](int rp) {
    const int c = rp * CPR + wid;
    if (c >= nch) return;
    const int buf = rp & 1;
    const float* rowp = logits + (size_t)b * (T_ * V_) + (size_t)c * (8 * V_);
    float4 X[16];
#pragma unroll
    for (int r = 0; r < 8; ++r) {  // issue all row loads up front (one HBM latency)
      X[2 * r] = *(const float4*)(rowp + r * V_ + 4 * lane);
      X[2 * r + 1] = *(const float4*)(rowp + r * V_ + 256 + 4 * lane);
    }
#pragma unroll
    for (int r = 0; r < 8; ++r) {
      const float4 xe = X[2 * r], xo = X[2 * r + 1];
      const float e0 = __expf(xe.x), e1 = __expf(xe.y), e2 = __expf(xe.z), e3 = __expf(xe.w);
      const float e4 = __expf(xo.x), e5 = __expf(xo.y), e6 = __expf(xo.z), e7 = __expf(xo.w);
      float s = ((e0 + e1) + (e2 + e3)) + ((e4 + e5) + (e6 + e7));
      DPPADD(s, 0x111, 0xf); DPPADD(s, 0x112, 0xf); DPPADD(s, 0x114, 0xf);
      DPPADD(s, 0x118, 0xf); DPPADD(s, 0x142, 0xa); DPPADD(s, 0x143, 0xc);
      const float sum = __int_as_float(__builtin_amdgcn_readlane(__float_as_int(s), 63));
      const float inv = 32.0f / sum;  // same x32 prescale as verified kernel
      float* sc = &scr[wid][r & 1][0];  // 2-slot alternation breaks reuse hazard
      *(float4*)(sc + 4 * lane) = make_float4(e0, e1, e2, e3);
      *(float4*)(sc + 256 + 4 * lane) = make_float4(e4, e5, e6, e7);
      asm volatile("s_waitcnt lgkmcnt(0)" ::: "memory");  // writes visible to all lanes
      float4 h;
      h.x = v0 ? sc[c4.x] * inv : 0.0f;  // LDS gather: ~2 lanes/bank, conflict-cheap
      h.y = v1 ? sc[c4.y] * inv : 0.0f;
      h.z = v2 ? sc[c4.z] * inv : 0.0f;
      h.w = v3 ? sc[c4.w] * inv : 0.0f;
      *(float4*)(&ring[buf][wid][r][4 * lane]) = h;
      if (lane == 0) ringbl[buf][wid][r] = e0 * inv;  // blank prob (class 0)
    }
  };

#define LDCHUNK(S, BUF, K)                                                   \
  {                                                                          \
    const int bf_ = (BUF), kk_ = (K);                                        \
    _Pragma("unroll") for (int u = 0; u < 8; ++u)                            \
        LQ##S[u] = *(const float4*)(&ring[bf_][kk_][u][4 * lane]);           \
    BLa##S = *(const float4*)(&ringbl[bf_][kk_][0]);                         \
    BLb##S = *(const float4*)(&ringbl[bf_][kk_][4]);                         \
  }

#define STEP8(S, CIDX, MASKED)                                               \
  {                                                                          \
    const int tf_ = (CIDX) * 8;                                              \
    const float blv_[8] = {BLa##S.x, BLa##S.y, BLa##S.z, BLa##S.w,           \
                           BLb##S.x, BLb##S.y, BLb##S.z, BLb##S.w};          \
    _Pragma("unroll") for (int u = 0; u < 8; ++u) {                          \
      const float4 hq = LQ##S[u];                                            \
      const float qx = hq.x, qy = hq.y, qz = hq.z, qw = hq.w;                \
      const float pbv = blv_[u];                                             \
      const float s1 = dpp_shr1_f(a7) * fac;  /* lane0 -> 0 */               \
      float n0 = (a0 + s1) * pbv;                                            \
      float n1 = fmaf(m0, s1, a0 + a1) * qx;                                 \
      float n2 = (a2 + a1) * pbv;                                            \
      float n3 = fmaf(m1, a1, a2 + a3) * qy;                                 \
      float n4 = (a4 + a3) * pbv;                                            \
      float n5 = fmaf(m2, a3, a4 + a5) * qz;                                 \
      float n6 = (a6 + a5) * pbv;                                            \
      float n7 = fmaf(m3, a5, a6 + a7) * qw;                                 \
      if (MASKED) {                                                          \
        const bool act = (tf_ + u) < len;                                    \
        n0 = act ? n0 : a0; n1 = act ? n1 : a1;                              \
        n2 = act ? n2 : a2; n3 = act ? n3 : a3;                              \
        n4 = act ? n4 : a4; n5 = act ? n5 : a5;                              \
        n6 = act ? n6 : a6; n7 = act ? n7 : a7;                              \
      }                                                                      \
      a0 = n0; a1 = n1; a2 = n2; a3 = n3;                                    \
      a4 = n4; a5 = n5; a6 = n6; a7 = n7;                                    \
    }                                                                        \
  }

#define RENORM                                                               \
  {                                                                          \
    const float mx = fmaxf(fmaxf(fmaxf(a0, a1), fmaxf(a2, a3)),              \
                           fmaxf(fmaxf(a4, a5), fmaxf(a6, a7)));             \
    const bool dead = (mx == 0.0f);                                          \
    int e_ = (int)((__float_as_uint(mx) >> 23) & 0xff) - 127;                \
    if (dead) e_ = 0;                                                        \
    const float sc_ = __int_as_float((unsigned)(127 - e_) << 23);            \
    a0 *= sc_; a1 *= sc_; a2 *= sc_; a3 *= sc_;                              \
    a4 *= sc_; a5 *= sc_; a6 *= sc_; a7 *= sc_;                              \
    const int En_ = E + e_;                                                  \
    const int EnP_ = dpp_shr1_i(En_);                                        \
    E = dead ? EnP_ : En_;                                                   \
    const int Ep_ = dpp_shr1_i(E);                                           \
    const int d_ = Ep_ - E;                                                  \
    int dc_ = d_ < -126 ? -126 : (d_ > 126 ? 126 : d_);                      \
    fac = (d_ < -126) ? 0.0f : __int_as_float((unsigned)(dc_ + 127) << 23);  \
  }

  // ================= barrier-paced pipeline =================
  if (wid < CPR) produce(0);
  __syncthreads();

  for (int r = 0; r < R; ++r) {
    if (wid < CPR) {
      if (r + 1 < R) produce(r + 1);
    } else {
      // consume the full (unmasked) chunks of round r from ring[r&1]
      const int c0 = r * CPR;
      int kn = nfull - c0;
      if (kn > CPR) kn = CPR;
      if (kn > 0) {
        LDCHUNK(0, r & 1, 0);
        for (int k = 0; k < kn; ++k) {  // ping-pong prefetch within the round
          if (k & 1) {
            if (k + 1 < kn) LDCHUNK(0, r & 1, k + 1);
            STEP8(1, 0, 0);
          } else {
            if (k + 1 < kn) LDCHUNK(1, r & 1, k + 1);
            STEP8(0, 0, 0);
          }
          RENORM;
        }
      }
    }
    __syncthreads();
  }

  if (wid == CPR) {
    if (rem) {  // deferred masked tail chunk; its ring slot was never overwritten
      const int cM = nfull;
      const int rM = cM / CPR;
      const int kM = cM - rM * CPR;
      LDCHUNK(0, rM & 1, kM);
      STEP8(0, cM, 1);
    }
    // ---- readout (single wave; in-wave LDS ordering) ----
    sval[lane * 8 + 0] = a0; sval[lane * 8 + 1] = a1;
    sval[lane * 8 + 2] = a2; sval[lane * 8 + 3] = a3;
    sval[lane * 8 + 4] = a4; sval[lane * 8 + 5] = a5;
    sval[lane * 8 + 6] = a6; sval[lane * 8 + 7] = a7;
    sE[lane] = E;
    asm volatile("s_waitcnt lgkmcnt(0)" ::: "memory");
    if (lane == 0) {
      const int tl = tl_s;
      const int e1 = 2 * tl;
      const int e2 = e1 - 1;
      const float v1r = sval[e1];
      const int E1 = sE[e1 >> 3];
      const float v2r = (e2 >= 0) ? sval[e2] : 0.0f;
      const int E2 = (e2 >= 0) ? sE[e2 >> 3] : E1;
      const int Em = (E1 > E2) ? E1 : E2;
      const float v = ldexpf(v1r, E1 - Em) + ldexpf(v2r, E2 - Em);
      // subtract len*ln(32) for the uniform x32 prob prescale
      const float ll = __logf(v) + (float)Em * 0.69314718056f - (float)len * 3.46573590280f;
      atomicAdd(out, -ll);
    }
  }
#undef LDCHUNK
#undef STEP8
#undef RENORM
}

extern "C" void kernel_launch(void* const* d_in, const int* in_sizes, int n_in,
                              void* d_out, int out_size, void* d_ws, size_t ws_size,
                              hipStream_t stream) {
  const float* logits = (const float*)d_in[0];     // [B,T,V] fp32 — read-only
  const int* input_lengths = (const int*)d_in[1];  // [B]
  const int* targets = (const int*)d_in[2];        // [B,L]
  float* out = (float*)d_out;                      // [1]
  (void)d_ws; (void)ws_size; (void)in_sizes; (void)n_in; (void)out_size;

  kz<<<1, 1, 0, stream>>>(out);
  ctc_fused<<<B_, 512, 0, stream>>>(logits, input_lengths, targets, out);
}

// Round 4
// 396.083 us; speedup vs baseline: 1.3207x; 1.1790x over previous
//
#include <hip/hip_runtime.h>

#define B_ 64
#define T_ 2000
#define V_ 512
#define L_ 200
#define CPR 7  // producer waves == chunks per round; 8 timesteps per chunk

// Fwd/bwd-split fused CTC. Grid = 128 blocks: block 2b = forward alpha of
// batch b (chunks [0, Cf)), block 2b+1 = backward gamma (chunks [Cf, nch),
// descending). Each block: 7 producer waves (softmax + LDS label-gather into
// a double-buffered fp32 ring) + 1 consumer wave (block-floating-point
// recursion), barrier-paced. Halves the serial depth per block and doubles
// CU usage (64 -> 128). Splice: P = sum_s alpha_{8Cf-1}[s] * delta[s] where
// delta = one emission-less backward step; combined by kcomb per batch.

__device__ __forceinline__ float dpp_shr1_f(float x) {  // lane i <- lane i-1; lane0 <- 0
  return __int_as_float(__builtin_amdgcn_update_dpp(0, __float_as_int(x), 0x138, 0xf, 0xf, true));
}
__device__ __forceinline__ int dpp_shr1_i(int x) {
  return __builtin_amdgcn_update_dpp(0, x, 0x138, 0xf, 0xf, true);
}
__device__ __forceinline__ float dpp_shl1_f(float x) {  // lane i <- lane i+1; lane63 <- 0
  return __int_as_float(__builtin_amdgcn_update_dpp(0, __float_as_int(x), 0x130, 0xf, 0xf, true));
}
__device__ __forceinline__ int dpp_shl1_i(int x) {
  return __builtin_amdgcn_update_dpp(0, x, 0x130, 0xf, 0xf, true);
}
#define DPPADD(v, ctrl, rmask)                                                              \
  v += __int_as_float(__builtin_amdgcn_update_dpp(0, __float_as_int(v), ctrl, rmask, 0xf, true));

__global__ void kz(float* __restrict__ out) { out[0] = 0.0f; }

__global__ __launch_bounds__(512, 1) void ctc_fused(const float* __restrict__ logits,
                                                    const int* __restrict__ lens,
                                                    const int* __restrict__ targets,
                                                    float* __restrict__ AF,
                                                    int* __restrict__ EF,
                                                    float* __restrict__ DD,
                                                    int* __restrict__ EB) {
  const int bx = blockIdx.x;
  const int b = bx >> 1;
  const int dirb = bx & 1;  // 0 = forward alpha, 1 = backward gamma
  const int wid = threadIdx.x >> 6;
  const int lane = threadIdx.x & 63;

  __shared__ __align__(16) float ring[2][CPR][8][256];  // 112 KB gathered fp32 probs
  __shared__ __align__(16) float ringbl[2][CPR][8];     // blank probs per timestep
  __shared__ __align__(16) float scr[CPR][2][512];      // 28 KB per-producer exp scratch
  __shared__ int cmp[256];                              // compacted nonzero targets
  __shared__ int tl_s;                                  // target length

  // ---- wave 0: compact targets ----
  if (wid == 0) {
    cmp[lane] = 0; cmp[64 + lane] = 0; cmp[128 + lane] = 0; cmp[192 + lane] = 0;
    int base = 0;
#pragma unroll
    for (int cc = 0; cc < 4; ++cc) {
      const int l = cc * 64 + lane;
      const int v = (l < L_) ? targets[b * L_ + l] : 0;
      const unsigned long long mk = __ballot(v != 0);
      const int pos = base + __popcll(mk & ((1ull << lane) - 1ull));
      if (v != 0) cmp[pos] = v;
      base += __popcll(mk);
    }
    if (lane == 0) tl_s = base;
  }
  __syncthreads();

  const int len = lens[b];
  const int nfull = len >> 3;
  const int rem = len & 7;
  const int nch = nfull + (rem ? 1 : 0);
  const int Cf = nch >> 1;          // forward handles chunks [0, Cf) - all full
  const int Ntot = dirb ? (nch - Cf) : Cf;
  const int R = (Ntot + CPR - 1) / CPR;
  const int4 c4 = *(const int4*)(&cmp[4 * lane]);

  const int l0 = 4 * lane;
  const bool v0 = l0 + 0 < L_, v1 = l0 + 1 < L_, v2 = l0 + 2 < L_, v3 = l0 + 3 < L_;

  // ---- consumer state (live on wave CPR only) ----
  float a0 = 0.f, a1 = 0.f, a2 = 0.f, a3 = 0.f, a4 = 0.f, a5 = 0.f, a6 = 0.f, a7 = 0.f;
  int E = 0;         // a_true = a_reg * 2^E (per lane)
  float fac = 1.0f;  // 2^(E_src_lane - E_this_lane)
  float m0 = 0.f, m1 = 0.f, m2 = 0.f, m3 = 0.f, m0n = 0.f;
  float4 LQ0[8], LQ1[8];
  float4 BLa0, BLb0, BLa1, BLb1;

  if (wid == CPR) {
    const int cm1 = __shfl_up(c4.w, 1);
    m0 = (lane > 0 && c4.x != 0 && c4.x != cm1) ? 1.0f : 0.0f;
    m1 = (c4.y != 0 && c4.y != c4.x) ? 1.0f : 0.0f;
    m2 = (c4.z != 0 && c4.z != c4.y) ? 1.0f : 0.0f;
    m3 = (c4.w != 0 && c4.w != c4.z) ? 1.0f : 0.0f;
    m0n = dpp_shl1_f(m0);  // skip mask from state 8i+7 into 8(i+1)+1
    if (!dirb) {
      // Seed: a0=1 on lane 0 -> chunk-0 step u=0 reproduces the alpha init.
      if (lane == 0) a0 = 1.0f;
    } else {
      // Seed: b[2*tl]=1 -> first backward step reproduces the gamma init.
      const int st = 2 * tl_s;
      if (lane == (st >> 3)) {
        const int e = st & 7;
        a0 = (e == 0) ? 1.0f : 0.0f; a1 = (e == 1) ? 1.0f : 0.0f;
        a2 = (e == 2) ? 1.0f : 0.0f; a3 = (e == 3) ? 1.0f : 0.0f;
        a4 = (e == 4) ? 1.0f : 0.0f; a5 = (e == 5) ? 1.0f : 0.0f;
        a6 = (e == 6) ? 1.0f : 0.0f; a7 = (e == 7) ? 1.0f : 0.0f;
      }
    }
    __builtin_amdgcn_s_setprio(1);  // consumer is the critical wave on its SIMD
  }

  // ---- producer body: build chunk c into ring[buf][wid] ----
  auto produce = [&](int c, int buf) {
    const float* rowp = logits + (size_t)b * (T_ * V_) + (size_t)c * (8 * V_);
    float4 X[16];
#pragma unroll
    for (int r = 0; r < 8; ++r) {  // issue all row loads up front (one HBM latency)
      X[2 * r] = *(const float4*)(rowp + r * V_ + 4 * lane);
      X[2 * r + 1] = *(const float4*)(rowp + r * V_ + 256 + 4 * lane);
    }
#pragma unroll
    for (int r = 0; r < 8; ++r) {
      const float4 xe = X[2 * r], xo = X[2 * r + 1];
      const float e0 = __expf(xe.x), e1 = __expf(xe.y), e2 = __expf(xe.z), e3 = __expf(xe.w);
      const float e4 = __expf(xo.x), e5 = __expf(xo.y), e6 = __expf(xo.z), e7 = __expf(xo.w);
      float s = ((e0 + e1) + (e2 + e3)) + ((e4 + e5) + (e6 + e7));
      DPPADD(s, 0x111, 0xf); DPPADD(s, 0x112, 0xf); DPPADD(s, 0x114, 0xf);
      DPPADD(s, 0x118, 0xf); DPPADD(s, 0x142, 0xa); DPPADD(s, 0x143, 0xc);
      const float sum = __int_as_float(__builtin_amdgcn_readlane(__float_as_int(s), 63));
      const float inv = 32.0f / sum;  // same x32 prescale as verified kernel
      float* sc = &scr[wid][r & 1][0];  // 2-slot alternation breaks reuse hazard
      *(float4*)(sc + 4 * lane) = make_float4(e0, e1, e2, e3);
      *(float4*)(sc + 256 + 4 * lane) = make_float4(e4, e5, e6, e7);
      asm volatile("s_waitcnt lgkmcnt(0)" ::: "memory");  // writes visible to all lanes
      float4 h;
      h.x = v0 ? sc[c4.x] * inv : 0.0f;  // LDS gather, conflict-cheap
      h.y = v1 ? sc[c4.y] * inv : 0.0f;
      h.z = v2 ? sc[c4.z] * inv : 0.0f;
      h.w = v3 ? sc[c4.w] * inv : 0.0f;
      *(float4*)(&ring[buf][wid][r][4 * lane]) = h;
      if (lane == 0) ringbl[buf][wid][r] = e0 * inv;  // blank prob (class 0)
    }
  };

#define LDCHUNK(S, BUF, K)                                                   \
  {                                                                          \
    const int bf_ = (BUF), kk_ = (K);                                        \
    _Pragma("unroll") for (int u = 0; u < 8; ++u)                            \
        LQ##S[u] = *(const float4*)(&ring[bf_][kk_][u][4 * lane]);           \
    BLa##S = *(const float4*)(&ringbl[bf_][kk_][0]);                         \
    BLb##S = *(const float4*)(&ringbl[bf_][kk_][4]);                         \
  }

// forward alpha step over 8 timesteps (ascending u); all chunks full
#define STEP8F(S)                                                            \
  {                                                                          \
    const float blv_[8] = {BLa##S.x, BLa##S.y, BLa##S.z, BLa##S.w,           \
                           BLb##S.x, BLb##S.y, BLb##S.z, BLb##S.w};          \
    _Pragma("unroll") for (int u = 0; u < 8; ++u) {                          \
      const float4 hq = LQ##S[u];                                            \
      const float pbv = blv_[u];                                             \
      const float s1 = dpp_shr1_f(a7) * fac;  /* lane0 -> 0 */               \
      float n0 = (a0 + s1) * pbv;                                            \
      float n1 = fmaf(m0, s1, a0 + a1) * hq.x;                               \
      float n2 = (a2 + a1) * pbv;                                            \
      float n3 = fmaf(m1, a1, a2 + a3) * hq.y;                               \
      float n4 = (a4 + a3) * pbv;                                            \
      float n5 = fmaf(m2, a3, a4 + a5) * hq.z;                               \
      float n6 = (a6 + a5) * pbv;                                            \
      float n7 = fmaf(m3, a5, a6 + a7) * hq.w;                               \
      a0 = n0; a1 = n1; a2 = n2; a3 = n3;                                    \
      a4 = n4; a5 = n5; a6 = n6; a7 = n7;                                    \
    }                                                                        \
  }

// backward gamma step over 8 timesteps (descending u); u > UHI skipped
#define STEP8B(S, UHI)                                                       \
  {                                                                          \
    const float blv_[8] = {BLa##S.x, BLa##S.y, BLa##S.z, BLa##S.w,           \
                           BLb##S.x, BLb##S.y, BLb##S.z, BLb##S.w};          \
    _Pragma("unroll") for (int u = 7; u >= 0; --u) {                         \
      if (u <= (UHI)) {                                                      \
        const float4 hq = LQ##S[u];                                          \
        const float pbv = blv_[u];                                           \
        const float sa = dpp_shl1_f(a0) * fac;  /* lane63 -> 0 */            \
        const float sb = dpp_shl1_f(a1) * fac;                               \
        float n0 = (a0 + a1) * pbv;                                          \
        float n1 = fmaf(m1, a3, a1 + a2) * hq.x;                             \
        float n2 = (a2 + a3) * pbv;                                          \
        float n3 = fmaf(m2, a5, a3 + a4) * hq.y;                             \
        float n4 = (a4 + a5) * pbv;                                          \
        float n5 = fmaf(m3, a7, a5 + a6) * hq.z;                             \
        float n6 = (a6 + a7) * pbv;                                          \
        float n7 = fmaf(m0n, sb, a7 + sa) * hq.w;                            \
        a0 = n0; a1 = n1; a2 = n2; a3 = n3;                                  \
        a4 = n4; a5 = n5; a6 = n6; a7 = n7;                                  \
      }                                                                      \
    }                                                                        \
  }

#define RENORM_COMMON                                                        \
    const float mx = fmaxf(fmaxf(fmaxf(a0, a1), fmaxf(a2, a3)),              \
                           fmaxf(fmaxf(a4, a5), fmaxf(a6, a7)));             \
    const bool dead = (mx == 0.0f);                                          \
    int e_ = (int)((__float_as_uint(mx) >> 23) & 0xff) - 127;                \
    if (dead) e_ = 0;                                                        \
    const float sc_ = __int_as_float((unsigned)(127 - e_) << 23);            \
    a0 *= sc_; a1 *= sc_; a2 *= sc_; a3 *= sc_;                              \
    a4 *= sc_; a5 *= sc_; a6 *= sc_; a7 *= sc_;                              \
    const int En_ = E + e_;

#define RENORMF                                                              \
  {                                                                          \
    RENORM_COMMON                                                            \
    const int EnP_ = dpp_shr1_i(En_);                                        \
    E = dead ? EnP_ : En_;                                                   \
    const int Ep_ = dpp_shr1_i(E);                                           \
    const int d_ = Ep_ - E;                                                  \
    int dc_ = d_ < -126 ? -126 : (d_ > 126 ? 126 : d_);                      \
    fac = (d_ < -126) ? 0.0f : __int_as_float((unsigned)(dc_ + 127) << 23);  \
  }

#define RENORMB                                                              \
  {                                                                          \
    RENORM_COMMON                                                            \
    const int EnP_ = dpp_shl1_i(En_);                                        \
    E = dead ? EnP_ : En_;                                                   \
    const int Ep_ = dpp_shl1_i(E);                                           \
    const int d_ = Ep_ - E;                                                  \
    int dc_ = d_ < -126 ? -126 : (d_ > 126 ? 126 : d_);                      \
    fac = (d_ < -126) ? 0.0f : __int_as_float((unsigned)(dc_ + 127) << 23);  \
  }

  // j = pipeline index (consumption order); chunk = fwd: j, bwd: nch-1-j
  // ================= barrier-paced pipeline =================
  if (wid < CPR) {
    const int j = wid;
    if (j < Ntot) produce(dirb ? (nch - 1 - j) : j, 0);
  }
  __syncthreads();

  for (int r = 0; r < R; ++r) {
    if (wid < CPR) {
      const int j = (r + 1) * CPR + wid;
      if (r + 1 < R && j < Ntot) produce(dirb ? (nch - 1 - j) : j, (r + 1) & 1);
    } else {
      int kn = Ntot - r * CPR;
      if (kn > CPR) kn = CPR;
      LDCHUNK(0, r & 1, 0);
      if (!dirb) {
        for (int k = 0; k < kn; ++k) {  // ping-pong prefetch within the round
          if (k & 1) {
            if (k + 1 < kn) LDCHUNK(0, r & 1, k + 1);
            STEP8F(1);
          } else {
            if (k + 1 < kn) LDCHUNK(1, r & 1, k + 1);
            STEP8F(0);
          }
          RENORMF;
        }
      } else {
        for (int k = 0; k < kn; ++k) {
          const int uh = (r == 0 && k == 0 && rem) ? (rem - 1) : 7;
          if (k & 1) {
            if (k + 1 < kn) LDCHUNK(0, r & 1, k + 1);
            STEP8B(1, uh);
          } else {
            if (k + 1 < kn) LDCHUNK(1, r & 1, k + 1);
            STEP8B(0, uh);
          }
          RENORMB;
        }
      }
    }
    __syncthreads();
  }

  // ---- epilogue: write block-float state for the combine kernel ----
  if (wid == CPR) {
    if (!dirb) {  // alpha_{8Cf-1}
      *(float4*)(AF + b * 512 + lane * 8) = make_float4(a0, a1, a2, a3);
      *(float4*)(AF + b * 512 + lane * 8 + 4) = make_float4(a4, a5, a6, a7);
      EF[b * 64 + lane] = E;
    } else {  // delta = emission-less backward step of gamma_{8Cf}
      const float sa = dpp_shl1_f(a0) * fac;
      const float sb = dpp_shl1_f(a1) * fac;
      const float d0 = a0 + a1;
      const float d1 = fmaf(m1, a3, a1 + a2);
      const float d2 = a2 + a3;
      const float d3 = fmaf(m2, a5, a3 + a4);
      const float d4 = a4 + a5;
      const float d5 = fmaf(m3, a7, a5 + a6);
      const float d6 = a6 + a7;
      const float d7 = fmaf(m0n, sb, a7 + sa);
      *(float4*)(DD + b * 512 + lane * 8) = make_float4(d0, d1, d2, d3);
      *(float4*)(DD + b * 512 + lane * 8 + 4) = make_float4(d4, d5, d6, d7);
      EB[b * 64 + lane] = E;
    }
  }
#undef LDCHUNK
#undef STEP8F
#undef STEP8B
#undef RENORM_COMMON
#undef RENORMF
#undef RENORMB
}

// ---- splice: -ll = -log( sum_s alpha[s]*delta[s] ) + len*ln(32) ----
__global__ __launch_bounds__(64) void kcomb(const int* __restrict__ lens,
                                            const float* __restrict__ AF,
                                            const int* __restrict__ EF,
                                            const float* __restrict__ DD,
                                            const int* __restrict__ EB,
                                            float* __restrict__ out) {
  const int b = blockIdx.x;
  const int lane = threadIdx.x;
  const float4 f0 = *(const float4*)(AF + b * 512 + lane * 8);
  const float4 f1 = *(const float4*)(AF + b * 512 + lane * 8 + 4);
  const float4 g0 = *(const float4*)(DD + b * 512 + lane * 8);
  const float4 g1 = *(const float4*)(DD + b * 512 + lane * 8 + 4);
  const float dot = ((f0.x * g0.x + f0.y * g0.y) + (f0.z * g0.z + f0.w * g0.w)) +
                    ((f1.x * g1.x + f1.y * g1.y) + (f1.z * g1.z + f1.w * g1.w));
  const int Es = EF[b * 64 + lane] + EB[b * 64 + lane];
  const bool z = (dot == 0.0f);
  int Ek = z ? (-(1 << 28)) : Es;
#pragma unroll
  for (int off = 32; off; off >>= 1) {
    const int o = __shfl_xor(Ek, off);
    Ek = o > Ek ? o : Ek;
  }
  float v = z ? 0.0f : ldexpf(dot, Es - Ek);
#pragma unroll
  for (int off = 32; off; off >>= 1) v += __shfl_xor(v, off);
  if (lane == 0) {
    const float ll = __logf(v) + (float)Ek * 0.69314718056f - (float)lens[b] * 3.46573590280f;
    atomicAdd(out, -ll);
  }
}

extern "C" void kernel_launch(void* const* d_in, const int* in_sizes, int n_in,
                              void* d_out, int out_size, void* d_ws, size_t ws_size,
                              hipStream_t stream) {
  const float* logits = (const float*)d_in[0];     // [B,T,V] fp32 — read-only
  const int* input_lengths = (const int*)d_in[1];  // [B]
  const int* targets = (const int*)d_in[2];        // [B,L]
  float* out = (float*)d_out;                      // [1]
  float* AF = (float*)d_ws;                        // [B][512]
  int* EF = (int*)(AF + B_ * 512);                 // [B][64]
  float* DD = (float*)(EF + B_ * 64);              // [B][512]
  int* EB = (int*)(DD + B_ * 512);                 // [B][64]
  (void)in_sizes; (void)n_in; (void)out_size; (void)ws_size;

  kz<<<1, 1, 0, stream>>>(out);
  ctc_fused<<<2 * B_, 512, 0, stream>>>(logits, input_lengths, targets, AF, EF, DD, EB);
  kcomb<<<B_, 64, 0, stream>>>(input_lengths, AF, EF, DD, EB, out);
}